// Round 4
// baseline (244.417 us; speedup 1.0000x reference)
//
#include <hip/hip_runtime.h>
#include <stdint.h>

#define RT    2336          // routes
#define RLDS  1568          // routes resident in LDS (bf16 quads, 8 B/slice)
#define RRES  (RT - RLDS)   // 768 residue routes: 6 register slices per thread
#define SCUT  12            // phase-A steps 0..SCUT-1 -> LDS, SCUT..17 -> regs
#define NRS   6             // register residue slots per thread (18 - SCUT)
#define NSL   13            // pass-2/3 LDS slice iterations (ceil(RLDS*4/512))
#define NTH   512
#define NBLK  2048          // one block per (b,k), XCD-pair swizzled
#define BATCH 1024
#define SH1   32.0f         // fixed softmax exponent shift, pass 2 (exact: ratio cancels)
#define SH2   64.0f         // fixed softmax exponent shift, pass 3

__device__ __forceinline__ float blo(uint32_t v){ union {uint32_t u; float f;} x; x.u = v << 16;        return x.f; }
__device__ __forceinline__ float bhi(uint32_t v){ union {uint32_t u; float f;} x; x.u = v & 0xffff0000u; return x.f; }
__device__ __forceinline__ uint32_t f2b1(float f){          // fp32 -> bf16 (RNE)
  union {float f; uint32_t u;} x; x.f = f;
  return (x.u + 0x7fffu + ((x.u >> 16) & 1u)) >> 16;
}
__device__ __forceinline__ uint32_t f2b_pack(float a, float b){ return f2b1(a) | (f2b1(b) << 16); }

// Quad (4-lane) all-reduce sum via DPP quad_perm: VALU pipe, no LDS traffic.
// quad_perm[1,0,3,2] = 0xB1 (xor 1), quad_perm[2,3,0,1] = 0x4E (xor 2).
__device__ __forceinline__ float qsum4(float d){
  d += __int_as_float(__builtin_amdgcn_update_dpp(
         0, __float_as_int(d), 0xB1, 0xF, 0xF, true));
  d += __int_as_float(__builtin_amdgcn_update_dpp(
         0, __float_as_int(d), 0x4E, 0xF, 0xF, true));
  return d;
}

// Quad-layout block merge: each lane holds (l, a[4]) for its o-quad qo = tid&3.
// Reduces over lanes with equal tid%4; final stage parallel over 16 lanes
// (lane o owns S[o]) instead of serial tid==0.
__device__ __forceinline__ void merge_quad(float4& a, float l, int tid,
                                           float (*red)[4][5], float* vbuf,
                                           bool last, float* out_cls){
  #pragma unroll
  for (int off = 32; off >= 4; off >>= 1){
    a.x += __shfl_down(a.x, off); a.y += __shfl_down(a.y, off);
    a.z += __shfl_down(a.z, off); a.w += __shfl_down(a.w, off);
    l   += __shfl_down(l,   off);
  }
  const int lane = tid & 63, wid = tid >> 6;
  if (lane < 4){
    red[wid][lane][0] = l;
    red[wid][lane][1] = a.x; red[wid][lane][2] = a.y;
    red[wid][lane][3] = a.z; red[wid][lane][4] = a.w;
  }
  __syncthreads();
  if (tid < 16){
    const int q = tid >> 2, j = tid & 3;   // lane owns output o = 4q + j
    float S = 0.f, partL = 0.f;
    #pragma unroll
    for (int w = 0; w < 8; ++w){
      S     += red[w][q][1 + j];
      partL += red[w][j][0];               // route-class j partial count
    }
    // total L = sum of the 4 route-classes, averaged (each counts all routes)
    partL += __shfl_xor(partL, 1);
    partL += __shfl_xor(partL, 2);
    float L   = partL * 0.25f;
    float inv = 1.f / L;
    float Sn  = S * inv;                   // s = acc / L
    float nrm = Sn * Sn;                   // squared norm, butterfly over 16 lanes
    nrm += __shfl_xor(nrm, 1);
    nrm += __shfl_xor(nrm, 2);
    nrm += __shfl_xor(nrm, 4);
    nrm += __shfl_xor(nrm, 8);
    if (last){
      if (tid == 0) *out_cls = nrm / (1.f + nrm);   // ||squash(s)|| = n/(1+n)
    } else {
      float f = sqrtf(nrm) / (1.f + nrm);           // squash scale on s
      vbuf[tid] = Sn * f;
    }
  }
  __syncthreads();
}

// LDS 50,880 B/block -> 3 blocks/CU (was 62 KB -> 2). 6 waves/SIMD needs
// VGPR <= 85; ~64 expected. launch_bounds 2nd arg = min waves per EU.
__global__ void __launch_bounds__(NTH, 6)
caps_route(const float* __restrict__ U, const float* __restrict__ W,
           float* __restrict__ Out){
  __shared__ uint2 uj[RLDS * 4];      // slice idx = route*4 + qo : bf16x4
  __shared__ float red[8][4][5];
  __shared__ float vbuf[16];

  const int tid = threadIdx.x;
  const int qo  = tid & 3;            // my o-quad: o = 4*qo .. 4*qo+3

  // XCD-pair swizzle: blocks i and i+8 land on the same XCD (dispatch is
  // round-robin over 8 XCDs) and get the same b with k=0/1 -> u[b] L2 reuse.
  const int c  = blockIdx.x & 7;
  const int jj = blockIdx.x >> 3;
  const int k  = jj & 1;
  const int b  = (c << 7) | (jj >> 1);

  const float* Ub = U + (size_t)b * (RT * 4);
  const float* Wk = W + (size_t)k * ((size_t)RT * 64) + qo * 4;

  float4 acc; float l;
  float  ur[NRS][4];                  // residue slices (routes RLDS..RT-1)
  float  d1[NSL], d1r[NRS];           // pass-2 dots, carried into pass 3
  float  vc0, vc1, vc2, vc3;          // my quad of v

  // u_ji quad for route r: uji[4qo+j] = sum_i u[b,r,i] * W[k,r,i,4qo+j]
  // W loads: lane stride 16 B inside 64-B lines -> fully coalesced.
  auto build_rq = [&](int route) -> float4 {
    float4 u4 = *(const float4*)(Ub + (size_t)route * 4);
    const float* wr = Wk + (size_t)route * 64;
    float4 w0 = *(const float4*)(wr);
    float4 w1 = *(const float4*)(wr + 16);
    float4 w2 = *(const float4*)(wr + 32);
    float4 w3 = *(const float4*)(wr + 48);
    float4 p;
    p.x = u4.x * w0.x; p.y = u4.x * w0.y; p.z = u4.x * w0.z; p.w = u4.x * w0.w;
    p.x = fmaf(u4.y, w1.x, p.x); p.y = fmaf(u4.y, w1.y, p.y);
    p.z = fmaf(u4.y, w1.z, p.z); p.w = fmaf(u4.y, w1.w, p.w);
    p.x = fmaf(u4.z, w2.x, p.x); p.y = fmaf(u4.z, w2.y, p.y);
    p.z = fmaf(u4.z, w2.z, p.z); p.w = fmaf(u4.z, w2.w, p.w);
    p.x = fmaf(u4.w, w3.x, p.x); p.y = fmaf(u4.w, w3.y, p.y);
    p.z = fmaf(u4.w, w3.z, p.z); p.w = fmaf(u4.w, w3.w, p.w);
    return p;
  };

  // ---------------- Phase A: build u_ji; fused pass 1 (uniform weights) ----
  acc = make_float4(0.f, 0.f, 0.f, 0.f); l = 0.f;

  if (tid < 128){                     // pre-step: routes 0..31
    int route = tid >> 2;
    float4 p = build_rq(route);
    acc.x += p.x; acc.y += p.y; acc.z += p.z; acc.w += p.w; l += 1.f;
    uj[route*4 + qo] = make_uint2(f2b_pack(p.x, p.y), f2b_pack(p.z, p.w));
  }
  #pragma unroll 3
  for (int s = 0; s < 18; ++s){       // routes 32 + 128*s + tid/4
    int route = 32 + s*128 + (tid >> 2);
    float4 p = build_rq(route);
    acc.x += p.x; acc.y += p.y; acc.z += p.z; acc.w += p.w; l += 1.f;
    if (s < SCUT){
      uj[route*4 + qo] = make_uint2(f2b_pack(p.x, p.y), f2b_pack(p.z, p.w));
    } else {
      int slot = s - SCUT;            // routes RLDS..2335 stay in registers
      ur[slot][0] = p.x; ur[slot][1] = p.y; ur[slot][2] = p.z; ur[slot][3] = p.w;
    }
  }
  merge_quad(acc, l, tid, red, vbuf, false, nullptr);   // v0
  vc0 = vbuf[4*qo]; vc1 = vbuf[4*qo+1]; vc2 = vbuf[4*qo+2]; vc3 = vbuf[4*qo+3];

  // ---------------- Pass 2: d = uji.v0 ; c = softmax(d); s1 ---------------
  acc = make_float4(0.f, 0.f, 0.f, 0.f); l = 0.f;
  #pragma unroll 4
  for (int s = 0; s < NSL; ++s){      // LDS slices, idx = tid + 512*s
    int idx = tid + (s << 9);
    bool act = (idx < RLDS * 4);      // only s==NSL-1 is partial (tid<128)
    float uf0=0.f, uf1=0.f, uf2=0.f, uf3=0.f, d = 0.f;
    if (act){
      uint2 q2 = uj[idx];
      uf0 = blo(q2.x); uf1 = bhi(q2.x); uf2 = blo(q2.y); uf3 = bhi(q2.y);
      d = fmaf(uf0, vc0, fmaf(uf1, vc1, fmaf(uf2, vc2, uf3 * vc3)));
    }
    d = qsum4(d);                     // full route dot to all 4 lanes (DPP)
    d1[s] = d;
    if (act){
      float e = __expf(d - SH1);
      l += e;
      acc.x = fmaf(e, uf0, acc.x); acc.y = fmaf(e, uf1, acc.y);
      acc.z = fmaf(e, uf2, acc.z); acc.w = fmaf(e, uf3, acc.w);
    }
  }
  #pragma unroll
  for (int slot = 0; slot < NRS; ++slot){           // residue slices
    float d = fmaf(ur[slot][0], vc0, fmaf(ur[slot][1], vc1,
              fmaf(ur[slot][2], vc2, ur[slot][3] * vc3)));
    d = qsum4(d);
    d1r[slot] = d;
    float e = __expf(d - SH1);
    l += e;
    acc.x = fmaf(e, ur[slot][0], acc.x); acc.y = fmaf(e, ur[slot][1], acc.y);
    acc.z = fmaf(e, ur[slot][2], acc.z); acc.w = fmaf(e, ur[slot][3], acc.w);
  }
  merge_quad(acc, l, tid, red, vbuf, false, nullptr);   // v1
  vc0 = vbuf[4*qo]; vc1 = vbuf[4*qo+1]; vc2 = vbuf[4*qo+2]; vc3 = vbuf[4*qo+3];

  // ---------------- Pass 3: b2 = d1 + uji.v1 ; c = softmax; s2 ------------
  acc = make_float4(0.f, 0.f, 0.f, 0.f); l = 0.f;
  #pragma unroll 4
  for (int s = 0; s < NSL; ++s){
    int idx = tid + (s << 9);
    bool act = (idx < RLDS * 4);
    float uf0=0.f, uf1=0.f, uf2=0.f, uf3=0.f, d = 0.f;
    if (act){
      uint2 q2 = uj[idx];
      uf0 = blo(q2.x); uf1 = bhi(q2.x); uf2 = blo(q2.y); uf3 = bhi(q2.y);
      d = fmaf(uf0, vc0, fmaf(uf1, vc1, fmaf(uf2, vc2, uf3 * vc3)));
    }
    d = qsum4(d);
    d += d1[s];
    if (act){
      float e = __expf(d - SH2);
      l += e;
      acc.x = fmaf(e, uf0, acc.x); acc.y = fmaf(e, uf1, acc.y);
      acc.z = fmaf(e, uf2, acc.z); acc.w = fmaf(e, uf3, acc.w);
    }
  }
  #pragma unroll
  for (int slot = 0; slot < NRS; ++slot){
    float d = fmaf(ur[slot][0], vc0, fmaf(ur[slot][1], vc1,
              fmaf(ur[slot][2], vc2, ur[slot][3] * vc3)));
    d = qsum4(d);
    d += d1r[slot];
    float e = __expf(d - SH2);
    l += e;
    acc.x = fmaf(e, ur[slot][0], acc.x); acc.y = fmaf(e, ur[slot][1], acc.y);
    acc.z = fmaf(e, ur[slot][2], acc.z); acc.w = fmaf(e, ur[slot][3], acc.w);
  }
  merge_quad(acc, l, tid, red, vbuf, true, Out + ((b << 1) | k));  // logit
}

// In-place 2-way softmax over k: Out[b,0..1] fp32
__global__ void caps_softmax(float* __restrict__ Out){
  int b = blockIdx.x * blockDim.x + threadIdx.x;
  if (b < BATCH){
    float2* p = (float2*)Out;
    float2 c = p[b];
    float m  = fmaxf(c.x, c.y);
    float e0 = __expf(c.x - m), e1 = __expf(c.y - m);
    float inv = 1.f / (e0 + e1);
    p[b] = make_float2(e0 * inv, e1 * inv);
  }
}

extern "C" void kernel_launch(void* const* d_in, const int* in_sizes, int n_in,
                              void* d_out, int out_size, void* d_ws, size_t ws_size,
                              hipStream_t stream) {
  const float* U = (const float*)d_in[0];   // [1024, 2336, 4] fp32
  const float* W = (const float*)d_in[1];   // [2, 2336, 4, 16] fp32
  float* Out = (float*)d_out;               // [1024, 2] fp32
  caps_route<<<dim3(NBLK), dim3(NTH), 0, stream>>>(U, W, Out);
  caps_softmax<<<dim3(BATCH / 256), dim3(256), 0, stream>>>(Out);
}

// Round 5
// 240.233 us; speedup vs baseline: 1.0174x; 1.0174x over previous
//
#include <hip/hip_runtime.h>
#include <stdint.h>

#define RT    2336          // routes
#define RLDS  1568          // routes resident in LDS (bf16 quads, 8 B/slice)
#define SCUT  12            // phase-A steps 0..SCUT-1 -> LDS, SCUT..17 -> regs
#define NRS   6             // register residue slots per thread (18 - SCUT)
#define NSL   13            // pass-2/3 LDS slice iterations (ceil(RLDS*4/512))
#define NTH   512
#define NBLK  2048          // one block per (b,k), XCD-pair swizzled
#define BATCH 1024
#define SH1   32.0f         // fixed softmax exponent shift, pass 2 (exact: ratio cancels)
#define SH2   64.0f         // fixed softmax exponent shift, pass 3

__device__ __forceinline__ float blo(uint32_t v){ union {uint32_t u; float f;} x; x.u = v << 16;        return x.f; }
__device__ __forceinline__ float bhi(uint32_t v){ union {uint32_t u; float f;} x; x.u = v & 0xffff0000u; return x.f; }
__device__ __forceinline__ uint32_t f2b1(float f){          // fp32 -> bf16 (RNE)
  union {float f; uint32_t u;} x; x.f = f;
  return (x.u + 0x7fffu + ((x.u >> 16) & 1u)) >> 16;
}
__device__ __forceinline__ uint32_t f2b_pack(float a, float b){ return f2b1(a) | (f2b1(b) << 16); }

// Quad (4-lane) all-reduce sum via DPP quad_perm: VALU pipe, no LDS traffic.
// quad_perm[1,0,3,2] = 0xB1 (xor 1), quad_perm[2,3,0,1] = 0x4E (xor 2).
__device__ __forceinline__ float qsum4(float d){
  d += __int_as_float(__builtin_amdgcn_update_dpp(
         0, __float_as_int(d), 0xB1, 0xF, 0xF, true));
  d += __int_as_float(__builtin_amdgcn_update_dpp(
         0, __float_as_int(d), 0x4E, 0xF, 0xF, true));
  return d;
}

// Quad-layout block merge: each lane holds (l, a[4]) for its o-quad qo = tid&3.
// Reduces over lanes with equal tid%4; final stage parallel over 16 lanes.
__device__ __forceinline__ void merge_quad(float4& a, float l, int tid,
                                           float (*red)[4][5], float* vbuf,
                                           bool last, float* out_cls){
  #pragma unroll
  for (int off = 32; off >= 4; off >>= 1){
    a.x += __shfl_down(a.x, off); a.y += __shfl_down(a.y, off);
    a.z += __shfl_down(a.z, off); a.w += __shfl_down(a.w, off);
    l   += __shfl_down(l,   off);
  }
  const int lane = tid & 63, wid = tid >> 6;
  if (lane < 4){
    red[wid][lane][0] = l;
    red[wid][lane][1] = a.x; red[wid][lane][2] = a.y;
    red[wid][lane][3] = a.z; red[wid][lane][4] = a.w;
  }
  __syncthreads();
  if (tid < 16){
    const int q = tid >> 2, j = tid & 3;   // lane owns output o = 4q + j
    float S = 0.f, partL = 0.f;
    #pragma unroll
    for (int w = 0; w < 8; ++w){
      S     += red[w][q][1 + j];
      partL += red[w][j][0];               // route-class j partial count
    }
    // total L = sum of the 4 route-classes, averaged (each counts all routes)
    partL += __shfl_xor(partL, 1);
    partL += __shfl_xor(partL, 2);
    float L   = partL * 0.25f;
    float inv = 1.f / L;
    float Sn  = S * inv;                   // s = acc / L
    float nrm = Sn * Sn;                   // squared norm, butterfly over 16 lanes
    nrm += __shfl_xor(nrm, 1);
    nrm += __shfl_xor(nrm, 2);
    nrm += __shfl_xor(nrm, 4);
    nrm += __shfl_xor(nrm, 8);
    if (last){
      if (tid == 0) *out_cls = nrm / (1.f + nrm);   // ||squash(s)|| = n/(1+n)
    } else {
      float f = sqrtf(nrm) / (1.f + nrm);           // squash scale on s
      vbuf[tid] = Sn * f;
    }
  }
  __syncthreads();
}

// LDS 50,880 B/block -> 3 blocks/CU = 6 waves/SIMD (VGPR cap 85).
// No pass-to-pass dot arrays: b2 = uji.(v0+v1), so vc accumulates v instead.
// All per-thread arrays statically indexed (full unrolls) -> no scratch.
__global__ void __launch_bounds__(NTH, 6)
caps_route(const float* __restrict__ U, const float* __restrict__ W,
           float* __restrict__ Out){
  __shared__ uint2 uj[RLDS * 4];      // slice idx = route*4 + qo : bf16x4
  __shared__ float red[8][4][5];
  __shared__ float vbuf[16];

  const int tid = threadIdx.x;
  const int qo  = tid & 3;            // my o-quad: o = 4*qo .. 4*qo+3

  // XCD-pair swizzle: blocks i and i+8 land on the same XCD (dispatch is
  // round-robin over 8 XCDs) and get the same b with k=0/1 -> u[b] L2 reuse.
  const int c  = blockIdx.x & 7;
  const int jj = blockIdx.x >> 3;
  const int k  = jj & 1;
  const int b  = (c << 7) | (jj >> 1);

  const float* Ub = U + (size_t)b * (RT * 4);
  const float* Wk = W + (size_t)k * ((size_t)RT * 64) + qo * 4;

  float4 acc; float l;
  float  ur[NRS][4];                  // residue slices (routes RLDS..RT-1)
  float  vc0, vc1, vc2, vc3;          // my quad of v (accumulates v0+v1)

  // u_ji quad for route r: uji[4qo+j] = sum_i u[b,r,i] * W[k,r,i,4qo+j]
  auto build_rq = [&](int route) -> float4 {
    float4 u4 = *(const float4*)(Ub + (size_t)route * 4);
    const float* wr = Wk + (size_t)route * 64;
    float4 w0 = *(const float4*)(wr);
    float4 w1 = *(const float4*)(wr + 16);
    float4 w2 = *(const float4*)(wr + 32);
    float4 w3 = *(const float4*)(wr + 48);
    float4 p;
    p.x = u4.x * w0.x; p.y = u4.x * w0.y; p.z = u4.x * w0.z; p.w = u4.x * w0.w;
    p.x = fmaf(u4.y, w1.x, p.x); p.y = fmaf(u4.y, w1.y, p.y);
    p.z = fmaf(u4.y, w1.z, p.z); p.w = fmaf(u4.y, w1.w, p.w);
    p.x = fmaf(u4.z, w2.x, p.x); p.y = fmaf(u4.z, w2.y, p.y);
    p.z = fmaf(u4.z, w2.z, p.z); p.w = fmaf(u4.z, w2.w, p.w);
    p.x = fmaf(u4.w, w3.x, p.x); p.y = fmaf(u4.w, w3.y, p.y);
    p.z = fmaf(u4.w, w3.z, p.z); p.w = fmaf(u4.w, w3.w, p.w);
    return p;
  };

  // ---------------- Phase A: build u_ji; fused pass 1 (uniform weights) ----
  acc = make_float4(0.f, 0.f, 0.f, 0.f); l = 0.f;

  if (tid < 128){                     // pre-step: routes 0..31
    int route = tid >> 2;
    float4 p = build_rq(route);
    acc.x += p.x; acc.y += p.y; acc.z += p.z; acc.w += p.w; l += 1.f;
    uj[route*4 + qo] = make_uint2(f2b_pack(p.x, p.y), f2b_pack(p.z, p.w));
  }
  #pragma unroll 3
  for (int s = 0; s < SCUT; ++s){     // LDS routes: 32 + 128*s + tid/4
    int route = 32 + s*128 + (tid >> 2);
    float4 p = build_rq(route);
    acc.x += p.x; acc.y += p.y; acc.z += p.z; acc.w += p.w; l += 1.f;
    uj[route*4 + qo] = make_uint2(f2b_pack(p.x, p.y), f2b_pack(p.z, p.w));
  }
  #pragma unroll
  for (int slot = 0; slot < NRS; ++slot){   // register routes, static slot
    int route = 32 + (SCUT + slot)*128 + (tid >> 2);
    float4 p = build_rq(route);
    acc.x += p.x; acc.y += p.y; acc.z += p.z; acc.w += p.w; l += 1.f;
    ur[slot][0] = p.x; ur[slot][1] = p.y; ur[slot][2] = p.z; ur[slot][3] = p.w;
  }
  merge_quad(acc, l, tid, red, vbuf, false, nullptr);   // v0
  vc0 = vbuf[4*qo]; vc1 = vbuf[4*qo+1]; vc2 = vbuf[4*qo+2]; vc3 = vbuf[4*qo+3];

  // ---------------- Pass 2: d = uji.v0 ; c = softmax(d); s1 ---------------
  acc = make_float4(0.f, 0.f, 0.f, 0.f); l = 0.f;
  #pragma unroll
  for (int s = 0; s < NSL; ++s){      // LDS slices, idx = tid + 512*s
    int idx = tid + (s << 9);
    bool act = (idx < RLDS * 4);      // only s==NSL-1 is partial (tid<128)
    float uf0=0.f, uf1=0.f, uf2=0.f, uf3=0.f, d = 0.f;
    if (act){
      uint2 q2 = uj[idx];
      uf0 = blo(q2.x); uf1 = bhi(q2.x); uf2 = blo(q2.y); uf3 = bhi(q2.y);
      d = fmaf(uf0, vc0, fmaf(uf1, vc1, fmaf(uf2, vc2, uf3 * vc3)));
    }
    d = qsum4(d);                     // full route dot to all 4 lanes (DPP)
    if (act){
      float e = __expf(d - SH1);
      l += e;
      acc.x = fmaf(e, uf0, acc.x); acc.y = fmaf(e, uf1, acc.y);
      acc.z = fmaf(e, uf2, acc.z); acc.w = fmaf(e, uf3, acc.w);
    }
  }
  #pragma unroll
  for (int slot = 0; slot < NRS; ++slot){           // residue slices
    float d = fmaf(ur[slot][0], vc0, fmaf(ur[slot][1], vc1,
              fmaf(ur[slot][2], vc2, ur[slot][3] * vc3)));
    d = qsum4(d);
    float e = __expf(d - SH1);
    l += e;
    acc.x = fmaf(e, ur[slot][0], acc.x); acc.y = fmaf(e, ur[slot][1], acc.y);
    acc.z = fmaf(e, ur[slot][2], acc.z); acc.w = fmaf(e, ur[slot][3], acc.w);
  }
  merge_quad(acc, l, tid, red, vbuf, false, nullptr);   // v1
  // b2 = uji.v0 + uji.v1 = uji.(v0+v1): accumulate v into vc
  vc0 += vbuf[4*qo]; vc1 += vbuf[4*qo+1]; vc2 += vbuf[4*qo+2]; vc3 += vbuf[4*qo+3];

  // ---------------- Pass 3: b2 = uji.(v0+v1) ; c = softmax; s2 ------------
  acc = make_float4(0.f, 0.f, 0.f, 0.f); l = 0.f;
  #pragma unroll
  for (int s = 0; s < NSL; ++s){
    int idx = tid + (s << 9);
    bool act = (idx < RLDS * 4);
    float uf0=0.f, uf1=0.f, uf2=0.f, uf3=0.f, d = 0.f;
    if (act){
      uint2 q2 = uj[idx];
      uf0 = blo(q2.x); uf1 = bhi(q2.x); uf2 = blo(q2.y); uf3 = bhi(q2.y);
      d = fmaf(uf0, vc0, fmaf(uf1, vc1, fmaf(uf2, vc2, uf3 * vc3)));
    }
    d = qsum4(d);
    if (act){
      float e = __expf(d - SH2);
      l += e;
      acc.x = fmaf(e, uf0, acc.x); acc.y = fmaf(e, uf1, acc.y);
      acc.z = fmaf(e, uf2, acc.z); acc.w = fmaf(e, uf3, acc.w);
    }
  }
  #pragma unroll
  for (int slot = 0; slot < NRS; ++slot){
    float d = fmaf(ur[slot][0], vc0, fmaf(ur[slot][1], vc1,
              fmaf(ur[slot][2], vc2, ur[slot][3] * vc3)));
    d = qsum4(d);
    float e = __expf(d - SH2);
    l += e;
    acc.x = fmaf(e, ur[slot][0], acc.x); acc.y = fmaf(e, ur[slot][1], acc.y);
    acc.z = fmaf(e, ur[slot][2], acc.z); acc.w = fmaf(e, ur[slot][3], acc.w);
  }
  merge_quad(acc, l, tid, red, vbuf, true, Out + ((b << 1) | k));  // logit
}

// In-place 2-way softmax over k: Out[b,0..1] fp32
__global__ void caps_softmax(float* __restrict__ Out){
  int b = blockIdx.x * blockDim.x + threadIdx.x;
  if (b < BATCH){
    float2* p = (float2*)Out;
    float2 c = p[b];
    float m  = fmaxf(c.x, c.y);
    float e0 = __expf(c.x - m), e1 = __expf(c.y - m);
    float inv = 1.f / (e0 + e1);
    p[b] = make_float2(e0 * inv, e1 * inv);
  }
}

extern "C" void kernel_launch(void* const* d_in, const int* in_sizes, int n_in,
                              void* d_out, int out_size, void* d_ws, size_t ws_size,
                              hipStream_t stream) {
  const float* U = (const float*)d_in[0];   // [1024, 2336, 4] fp32
  const float* W = (const float*)d_in[1];   // [2, 2336, 4, 16] fp32
  float* Out = (float*)d_out;               // [1024, 2] fp32
  caps_route<<<dim3(NBLK), dim3(NTH), 0, stream>>>(U, W, Out);
  caps_softmax<<<dim3(BATCH / 256), dim3(256), 0, stream>>>(Out);
}

// Round 7
// 154.183 us; speedup vs baseline: 1.5852x; 1.5581x over previous
//
#include <hip/hip_runtime.h>
#include <stdint.h>

#define RT    2336          // routes
#define RLDS  1568          // routes resident in LDS (bf16 quads, 8 B/slice)
#define SCUT  12            // phase-A steps 0..SCUT-1 -> LDS, SCUT..17 -> regs
#define NRS   6             // register residue slots per thread (18 - SCUT)
#define NSL   13            // pass-2/3 LDS slice iterations (ceil(RLDS*4/512))
#define NTH   512
#define NBLK  2048          // one block per (b,k), XCD-pair swizzled
#define BATCH 1024
#define SH1   32.0f         // fixed softmax exponent shift, pass 2 (exact: ratio cancels)
#define SH2   64.0f         // fixed softmax exponent shift, pass 3

__device__ __forceinline__ float blo(uint32_t v){ union {uint32_t u; float f;} x; x.u = v << 16;        return x.f; }
__device__ __forceinline__ float bhi(uint32_t v){ union {uint32_t u; float f;} x; x.u = v & 0xffff0000u; return x.f; }
__device__ __forceinline__ uint32_t f2b1(float f){          // fp32 -> bf16 (RNE)
  union {float f; uint32_t u;} x; x.f = f;
  return (x.u + 0x7fffu + ((x.u >> 16) & 1u)) >> 16;
}
__device__ __forceinline__ uint32_t f2b_pack(float a, float b){ return f2b1(a) | (f2b1(b) << 16); }

// Quad (4-lane) all-reduce sum via DPP quad_perm: VALU pipe, no LDS traffic.
// quad_perm[1,0,3,2] = 0xB1 (xor 1), quad_perm[2,3,0,1] = 0x4E (xor 2).
__device__ __forceinline__ float qsum4(float d){
  d += __int_as_float(__builtin_amdgcn_update_dpp(
         0, __float_as_int(d), 0xB1, 0xF, 0xF, true));
  d += __int_as_float(__builtin_amdgcn_update_dpp(
         0, __float_as_int(d), 0x4E, 0xF, 0xF, true));
  return d;
}

// Quad-layout block merge: each lane holds (l, a[4]) for its o-quad qo = tid&3.
// Reduces over lanes with equal tid%4; final stage parallel over 16 lanes.
__device__ __forceinline__ void merge_quad(float4& a, float l, int tid,
                                           float (*red)[4][5], float* vbuf,
                                           bool last, float* out_cls){
  #pragma unroll
  for (int off = 32; off >= 4; off >>= 1){
    a.x += __shfl_down(a.x, off); a.y += __shfl_down(a.y, off);
    a.z += __shfl_down(a.z, off); a.w += __shfl_down(a.w, off);
    l   += __shfl_down(l,   off);
  }
  const int lane = tid & 63, wid = tid >> 6;
  if (lane < 4){
    red[wid][lane][0] = l;
    red[wid][lane][1] = a.x; red[wid][lane][2] = a.y;
    red[wid][lane][3] = a.z; red[wid][lane][4] = a.w;
  }
  __syncthreads();
  if (tid < 16){
    const int q = tid >> 2, j = tid & 3;   // lane owns output o = 4q + j
    float S = 0.f, partL = 0.f;
    #pragma unroll
    for (int w = 0; w < 8; ++w){
      S     += red[w][q][1 + j];
      partL += red[w][j][0];               // route-class j partial count
    }
    // total L = sum of the 4 route-classes, averaged (each counts all routes)
    partL += __shfl_xor(partL, 1);
    partL += __shfl_xor(partL, 2);
    float L   = partL * 0.25f;
    float inv = 1.f / L;
    float Sn  = S * inv;                   // s = acc / L
    float nrm = Sn * Sn;                   // squared norm, butterfly over 16 lanes
    nrm += __shfl_xor(nrm, 1);
    nrm += __shfl_xor(nrm, 2);
    nrm += __shfl_xor(nrm, 4);
    nrm += __shfl_xor(nrm, 8);
    if (last){
      if (tid == 0) *out_cls = nrm / (1.f + nrm);   // ||squash(s)|| = n/(1+n)
    } else {
      float f = sqrtf(nrm) / (1.f + nrm);           // squash scale on s
      vbuf[tid] = Sn * f;
    }
  }
  __syncthreads();
}

// LDS 50,880 B/block -> 3 blocks/CU = 6 waves/SIMD.
// __launch_bounds__ 2nd arg: empirically MIN BLOCKS PER CU on this toolchain
// (arg=6 produced a 12-waves/SIMD VGPR cap of 40 -> 430 MB spill, R4/R5;
//  arg=4 -> cap 64, VGPR 52, no spill, R3). arg=3 -> cap ~85, no spill.
__global__ void __launch_bounds__(NTH, 3)
caps_route(const float* __restrict__ U, const float* __restrict__ W,
           float* __restrict__ Out){
  __shared__ uint2 uj[RLDS * 4];      // slice idx = route*4 + qo : bf16x4
  __shared__ float red[8][4][5];
  __shared__ float vbuf[16];

  const int tid = threadIdx.x;
  const int qo  = tid & 3;            // my o-quad: o = 4*qo .. 4*qo+3

  // XCD-pair swizzle: blocks i and i+8 land on the same XCD (dispatch is
  // round-robin over 8 XCDs) and get the same b with k=0/1 -> u[b] L2 reuse.
  const int c  = blockIdx.x & 7;
  const int jj = blockIdx.x >> 3;
  const int k  = jj & 1;
  const int b  = (c << 7) | (jj >> 1);

  const float* Ub = U + (size_t)b * (RT * 4);
  const float* Wk = W + (size_t)k * ((size_t)RT * 64) + qo * 4;

  float4 acc; float l;
  float  ur[NRS][4];                  // residue slices (routes RLDS..RT-1)
  float  vc0, vc1, vc2, vc3;          // my quad of v (accumulates v0+v1)

  // u_ji quad for route r: uji[4qo+j] = sum_i u[b,r,i] * W[k,r,i,4qo+j]
  auto build_rq = [&](int route) -> float4 {
    float4 u4 = *(const float4*)(Ub + (size_t)route * 4);
    const float* wr = Wk + (size_t)route * 64;
    float4 w0 = *(const float4*)(wr);
    float4 w1 = *(const float4*)(wr + 16);
    float4 w2 = *(const float4*)(wr + 32);
    float4 w3 = *(const float4*)(wr + 48);
    float4 p;
    p.x = u4.x * w0.x; p.y = u4.x * w0.y; p.z = u4.x * w0.z; p.w = u4.x * w0.w;
    p.x = fmaf(u4.y, w1.x, p.x); p.y = fmaf(u4.y, w1.y, p.y);
    p.z = fmaf(u4.y, w1.z, p.z); p.w = fmaf(u4.y, w1.w, p.w);
    p.x = fmaf(u4.z, w2.x, p.x); p.y = fmaf(u4.z, w2.y, p.y);
    p.z = fmaf(u4.z, w2.z, p.z); p.w = fmaf(u4.z, w2.w, p.w);
    p.x = fmaf(u4.w, w3.x, p.x); p.y = fmaf(u4.w, w3.y, p.y);
    p.z = fmaf(u4.w, w3.z, p.z); p.w = fmaf(u4.w, w3.w, p.w);
    return p;
  };

  // ---------------- Phase A: build u_ji; fused pass 1 (uniform weights) ----
  acc = make_float4(0.f, 0.f, 0.f, 0.f); l = 0.f;

  if (tid < 128){                     // pre-step: routes 0..31
    int route = tid >> 2;
    float4 p = build_rq(route);
    acc.x += p.x; acc.y += p.y; acc.z += p.z; acc.w += p.w; l += 1.f;
    uj[route*4 + qo] = make_uint2(f2b_pack(p.x, p.y), f2b_pack(p.z, p.w));
  }
  #pragma unroll 3
  for (int s = 0; s < SCUT; ++s){     // LDS routes: 32 + 128*s + tid/4
    int route = 32 + s*128 + (tid >> 2);
    float4 p = build_rq(route);
    acc.x += p.x; acc.y += p.y; acc.z += p.z; acc.w += p.w; l += 1.f;
    uj[route*4 + qo] = make_uint2(f2b_pack(p.x, p.y), f2b_pack(p.z, p.w));
  }
  #pragma unroll
  for (int slot = 0; slot < NRS; ++slot){   // register routes, static slot
    int route = 32 + (SCUT + slot)*128 + (tid >> 2);
    float4 p = build_rq(route);
    acc.x += p.x; acc.y += p.y; acc.z += p.z; acc.w += p.w; l += 1.f;
    ur[slot][0] = p.x; ur[slot][1] = p.y; ur[slot][2] = p.z; ur[slot][3] = p.w;
  }
  merge_quad(acc, l, tid, red, vbuf, false, nullptr);   // v0
  vc0 = vbuf[4*qo]; vc1 = vbuf[4*qo+1]; vc2 = vbuf[4*qo+2]; vc3 = vbuf[4*qo+3];

  // ---------------- Pass 2: d = uji.v0 ; c = softmax(d); s1 ---------------
  acc = make_float4(0.f, 0.f, 0.f, 0.f); l = 0.f;
  #pragma unroll
  for (int s = 0; s < NSL; ++s){      // LDS slices, idx = tid + 512*s
    int idx = tid + (s << 9);
    bool act = (idx < RLDS * 4);      // only s==NSL-1 is partial (tid<128)
    float uf0=0.f, uf1=0.f, uf2=0.f, uf3=0.f, d = 0.f;
    if (act){
      uint2 q2 = uj[idx];
      uf0 = blo(q2.x); uf1 = bhi(q2.x); uf2 = blo(q2.y); uf3 = bhi(q2.y);
      d = fmaf(uf0, vc0, fmaf(uf1, vc1, fmaf(uf2, vc2, uf3 * vc3)));
    }
    d = qsum4(d);                     // full route dot to all 4 lanes (DPP)
    if (act){
      float e = __expf(d - SH1);
      l += e;
      acc.x = fmaf(e, uf0, acc.x); acc.y = fmaf(e, uf1, acc.y);
      acc.z = fmaf(e, uf2, acc.z); acc.w = fmaf(e, uf3, acc.w);
    }
  }
  #pragma unroll
  for (int slot = 0; slot < NRS; ++slot){           // residue slices
    float d = fmaf(ur[slot][0], vc0, fmaf(ur[slot][1], vc1,
              fmaf(ur[slot][2], vc2, ur[slot][3] * vc3)));
    d = qsum4(d);
    float e = __expf(d - SH1);
    l += e;
    acc.x = fmaf(e, ur[slot][0], acc.x); acc.y = fmaf(e, ur[slot][1], acc.y);
    acc.z = fmaf(e, ur[slot][2], acc.z); acc.w = fmaf(e, ur[slot][3], acc.w);
  }
  merge_quad(acc, l, tid, red, vbuf, false, nullptr);   // v1
  // b2 = uji.v0 + uji.v1 = uji.(v0+v1): accumulate v into vc
  vc0 += vbuf[4*qo]; vc1 += vbuf[4*qo+1]; vc2 += vbuf[4*qo+2]; vc3 += vbuf[4*qo+3];

  // ---------------- Pass 3: b2 = uji.(v0+v1) ; c = softmax; s2 ------------
  acc = make_float4(0.f, 0.f, 0.f, 0.f); l = 0.f;
  #pragma unroll
  for (int s = 0; s < NSL; ++s){
    int idx = tid + (s << 9);
    bool act = (idx < RLDS * 4);
    float uf0=0.f, uf1=0.f, uf2=0.f, uf3=0.f, d = 0.f;
    if (act){
      uint2 q2 = uj[idx];
      uf0 = blo(q2.x); uf1 = bhi(q2.x); uf2 = blo(q2.y); uf3 = bhi(q2.y);
      d = fmaf(uf0, vc0, fmaf(uf1, vc1, fmaf(uf2, vc2, uf3 * vc3)));
    }
    d = qsum4(d);
    if (act){
      float e = __expf(d - SH2);
      l += e;
      acc.x = fmaf(e, uf0, acc.x); acc.y = fmaf(e, uf1, acc.y);
      acc.z = fmaf(e, uf2, acc.z); acc.w = fmaf(e, uf3, acc.w);
    }
  }
  #pragma unroll
  for (int slot = 0; slot < NRS; ++slot){
    float d = fmaf(ur[slot][0], vc0, fmaf(ur[slot][1], vc1,
              fmaf(ur[slot][2], vc2, ur[slot][3] * vc3)));
    d = qsum4(d);
    float e = __expf(d - SH2);
    l += e;
    acc.x = fmaf(e, ur[slot][0], acc.x); acc.y = fmaf(e, ur[slot][1], acc.y);
    acc.z = fmaf(e, ur[slot][2], acc.z); acc.w = fmaf(e, ur[slot][3], acc.w);
  }
  merge_quad(acc, l, tid, red, vbuf, true, Out + ((b << 1) | k));  // logit
}

// In-place 2-way softmax over k: Out[b,0..1] fp32
__global__ void caps_softmax(float* __restrict__ Out){
  int b = blockIdx.x * blockDim.x + threadIdx.x;
  if (b < BATCH){
    float2* p = (float2*)Out;
    float2 c = p[b];
    float m  = fmaxf(c.x, c.y);
    float e0 = __expf(c.x - m), e1 = __expf(c.y - m);
    float inv = 1.f / (e0 + e1);
    p[b] = make_float2(e0 * inv, e1 * inv);
  }
}

extern "C" void kernel_launch(void* const* d_in, const int* in_sizes, int n_in,
                              void* d_out, int out_size, void* d_ws, size_t ws_size,
                              hipStream_t stream) {
  const float* U = (const float*)d_in[0];   // [1024, 2336, 4] fp32
  const float* W = (const float*)d_in[1];   // [2, 2336, 4, 16] fp32
  float* Out = (float*)d_out;               // [1024, 2] fp32
  caps_route<<<dim3(NBLK), dim3(NTH), 0, stream>>>(U, W, Out);
  caps_softmax<<<dim3(BATCH / 256), dim3(256), 0, stream>>>(Out);
}

// Round 9
// 140.925 us; speedup vs baseline: 1.7344x; 1.0941x over previous
//
#include <hip/hip_runtime.h>
#include <stdint.h>

#define RT    2336          // routes
#define RLDS  1568          // routes resident in LDS (bf16 quads, 8 B/slice)
#define SCUT  12            // phase-A steps 0..SCUT-1 -> LDS, SCUT..17 -> regs
#define NRS   6             // register residue slots per thread (18 - SCUT)
#define NSL   13            // pass-2/3 LDS slice iterations (ceil(RLDS*4/512))
#define NTH   512
#define NBLK  2048          // one block per (b,k), XCD-pair swizzled
#define BATCH 1024
#define SH1   32.0f         // fixed softmax exponent shift, pass 2 (exact: ratio cancels)
#define SH2   64.0f         // fixed softmax exponent shift, pass 3

__device__ __forceinline__ float blo(uint32_t v){ union {uint32_t u; float f;} x; x.u = v << 16;        return x.f; }
__device__ __forceinline__ float bhi(uint32_t v){ union {uint32_t u; float f;} x; x.u = v & 0xffff0000u; return x.f; }
__device__ __forceinline__ uint32_t f2b1(float f){          // fp32 -> bf16 (RNE)
  union {float f; uint32_t u;} x; x.f = f;
  return (x.u + 0x7fffu + ((x.u >> 16) & 1u)) >> 16;
}
__device__ __forceinline__ uint32_t f2b_pack(float a, float b){ return f2b1(a) | (f2b1(b) << 16); }

// Quad (4-lane) all-reduce sum via DPP quad_perm: VALU pipe, no LDS traffic.
// quad_perm[1,0,3,2] = 0xB1 (xor 1), quad_perm[2,3,0,1] = 0x4E (xor 2).
__device__ __forceinline__ float qsum4(float d){
  d += __int_as_float(__builtin_amdgcn_update_dpp(
         0, __float_as_int(d), 0xB1, 0xF, 0xF, true));
  d += __int_as_float(__builtin_amdgcn_update_dpp(
         0, __float_as_int(d), 0x4E, 0xF, 0xF, true));
  return d;
}

// Quad-layout block merge: each lane holds (l, a[4]) for its o-quad qo = tid&3.
// Reduces over lanes with equal tid%4; final stage parallel over 16 lanes.
__device__ __forceinline__ void merge_quad(float4& a, float l, int tid,
                                           float (*red)[4][5], float* vbuf,
                                           bool last, float* out_cls){
  #pragma unroll
  for (int off = 32; off >= 4; off >>= 1){
    a.x += __shfl_down(a.x, off); a.y += __shfl_down(a.y, off);
    a.z += __shfl_down(a.z, off); a.w += __shfl_down(a.w, off);
    l   += __shfl_down(l,   off);
  }
  const int lane = tid & 63, wid = tid >> 6;
  if (lane < 4){
    red[wid][lane][0] = l;
    red[wid][lane][1] = a.x; red[wid][lane][2] = a.y;
    red[wid][lane][3] = a.z; red[wid][lane][4] = a.w;
  }
  __syncthreads();
  if (tid < 16){
    const int q = tid >> 2, j = tid & 3;   // lane owns output o = 4q + j
    float S = 0.f, partL = 0.f;
    #pragma unroll
    for (int w = 0; w < 8; ++w){
      S     += red[w][q][1 + j];
      partL += red[w][j][0];               // route-class j partial count
    }
    // total L = sum of the 4 route-classes, averaged (each counts all routes)
    partL += __shfl_xor(partL, 1);
    partL += __shfl_xor(partL, 2);
    float L   = partL * 0.25f;
    float inv = 1.f / L;
    float Sn  = S * inv;                   // s = acc / L
    float nrm = Sn * Sn;                   // squared norm, butterfly over 16 lanes
    nrm += __shfl_xor(nrm, 1);
    nrm += __shfl_xor(nrm, 2);
    nrm += __shfl_xor(nrm, 4);
    nrm += __shfl_xor(nrm, 8);
    if (last){
      if (tid == 0) *out_cls = nrm / (1.f + nrm);   // ||squash(s)|| = n/(1+n)
    } else {
      float f = sqrtf(nrm) / (1.f + nrm);           // squash scale on s
      vbuf[tid] = Sn * f;
    }
  }
  __syncthreads();
}

// LDS 50,880 B/block -> 3 blocks/CU possible. Session-empirical launch_bounds
// model: VGPR cap = 512/(2*arg). arg=6 -> cap 40 (spilled 430 MB, R4/R5);
// arg=3 -> cap 85, compiler used 68 -> crossed the 64-VGPR occupancy knee
// (waves/SIMD 8->4, occupancy 21%, R7). arg=4 -> cap 64 = exactly the knee;
// R3's heavier body fit in 52 under this cap, this lighter body should too.
__global__ void __launch_bounds__(NTH, 4)
caps_route(const float* __restrict__ U, const float* __restrict__ W,
           float* __restrict__ Out){
  __shared__ uint2 uj[RLDS * 4];      // slice idx = route*4 + qo : bf16x4
  __shared__ float red[8][4][5];
  __shared__ float vbuf[16];

  const int tid = threadIdx.x;
  const int qo  = tid & 3;            // my o-quad: o = 4*qo .. 4*qo+3

  // XCD-pair swizzle: blocks i and i+8 land on the same XCD (dispatch is
  // round-robin over 8 XCDs) and get the same b with k=0/1 -> u[b] L2 reuse.
  const int c  = blockIdx.x & 7;
  const int jj = blockIdx.x >> 3;
  const int k  = jj & 1;
  const int b  = (c << 7) | (jj >> 1);

  const float* Ub = U + (size_t)b * (RT * 4);
  const float* Wk = W + (size_t)k * ((size_t)RT * 64) + qo * 4;

  float4 acc; float l;
  float  ur[NRS][4];                  // residue slices (routes RLDS..RT-1)
  float  vc0, vc1, vc2, vc3;          // my quad of v (accumulates v0+v1)

  // u_ji quad for route r: uji[4qo+j] = sum_i u[b,r,i] * W[k,r,i,4qo+j]
  auto build_rq = [&](int route) -> float4 {
    float4 u4 = *(const float4*)(Ub + (size_t)route * 4);
    const float* wr = Wk + (size_t)route * 64;
    float4 w0 = *(const float4*)(wr);
    float4 w1 = *(const float4*)(wr + 16);
    float4 w2 = *(const float4*)(wr + 32);
    float4 w3 = *(const float4*)(wr + 48);
    float4 p;
    p.x = u4.x * w0.x; p.y = u4.x * w0.y; p.z = u4.x * w0.z; p.w = u4.x * w0.w;
    p.x = fmaf(u4.y, w1.x, p.x); p.y = fmaf(u4.y, w1.y, p.y);
    p.z = fmaf(u4.y, w1.z, p.z); p.w = fmaf(u4.y, w1.w, p.w);
    p.x = fmaf(u4.z, w2.x, p.x); p.y = fmaf(u4.z, w2.y, p.y);
    p.z = fmaf(u4.z, w2.z, p.z); p.w = fmaf(u4.z, w2.w, p.w);
    p.x = fmaf(u4.w, w3.x, p.x); p.y = fmaf(u4.w, w3.y, p.y);
    p.z = fmaf(u4.w, w3.z, p.z); p.w = fmaf(u4.w, w3.w, p.w);
    return p;
  };

  // ---------------- Phase A: build u_ji; fused pass 1 (uniform weights) ----
  acc = make_float4(0.f, 0.f, 0.f, 0.f); l = 0.f;

  if (tid < 128){                     // pre-step: routes 0..31
    int route = tid >> 2;
    float4 p = build_rq(route);
    acc.x += p.x; acc.y += p.y; acc.z += p.z; acc.w += p.w; l += 1.f;
    uj[route*4 + qo] = make_uint2(f2b_pack(p.x, p.y), f2b_pack(p.z, p.w));
  }
  #pragma unroll 3
  for (int s = 0; s < SCUT; ++s){     // LDS routes: 32 + 128*s + tid/4
    int route = 32 + s*128 + (tid >> 2);
    float4 p = build_rq(route);
    acc.x += p.x; acc.y += p.y; acc.z += p.z; acc.w += p.w; l += 1.f;
    uj[route*4 + qo] = make_uint2(f2b_pack(p.x, p.y), f2b_pack(p.z, p.w));
  }
  #pragma unroll
  for (int slot = 0; slot < NRS; ++slot){   // register routes, static slot
    int route = 32 + (SCUT + slot)*128 + (tid >> 2);
    float4 p = build_rq(route);
    acc.x += p.x; acc.y += p.y; acc.z += p.z; acc.w += p.w; l += 1.f;
    ur[slot][0] = p.x; ur[slot][1] = p.y; ur[slot][2] = p.z; ur[slot][3] = p.w;
  }
  merge_quad(acc, l, tid, red, vbuf, false, nullptr);   // v0
  vc0 = vbuf[4*qo]; vc1 = vbuf[4*qo+1]; vc2 = vbuf[4*qo+2]; vc3 = vbuf[4*qo+3];

  // ---------------- Pass 2: d = uji.v0 ; c = softmax(d); s1 ---------------
  acc = make_float4(0.f, 0.f, 0.f, 0.f); l = 0.f;
  #pragma unroll
  for (int s = 0; s < NSL; ++s){      // LDS slices, idx = tid + 512*s
    int idx = tid + (s << 9);
    bool act = (idx < RLDS * 4);      // only s==NSL-1 is partial (tid<128)
    float uf0=0.f, uf1=0.f, uf2=0.f, uf3=0.f, d = 0.f;
    if (act){
      uint2 q2 = uj[idx];
      uf0 = blo(q2.x); uf1 = bhi(q2.x); uf2 = blo(q2.y); uf3 = bhi(q2.y);
      d = fmaf(uf0, vc0, fmaf(uf1, vc1, fmaf(uf2, vc2, uf3 * vc3)));
    }
    d = qsum4(d);                     // full route dot to all 4 lanes (DPP)
    if (act){
      float e = __expf(d - SH1);
      l += e;
      acc.x = fmaf(e, uf0, acc.x); acc.y = fmaf(e, uf1, acc.y);
      acc.z = fmaf(e, uf2, acc.z); acc.w = fmaf(e, uf3, acc.w);
    }
  }
  #pragma unroll
  for (int slot = 0; slot < NRS; ++slot){           // residue slices
    float d = fmaf(ur[slot][0], vc0, fmaf(ur[slot][1], vc1,
              fmaf(ur[slot][2], vc2, ur[slot][3] * vc3)));
    d = qsum4(d);
    float e = __expf(d - SH1);
    l += e;
    acc.x = fmaf(e, ur[slot][0], acc.x); acc.y = fmaf(e, ur[slot][1], acc.y);
    acc.z = fmaf(e, ur[slot][2], acc.z); acc.w = fmaf(e, ur[slot][3], acc.w);
  }
  merge_quad(acc, l, tid, red, vbuf, false, nullptr);   // v1
  // b2 = uji.v0 + uji.v1 = uji.(v0+v1): accumulate v into vc
  vc0 += vbuf[4*qo]; vc1 += vbuf[4*qo+1]; vc2 += vbuf[4*qo+2]; vc3 += vbuf[4*qo+3];

  // ---------------- Pass 3: b2 = uji.(v0+v1) ; c = softmax; s2 ------------
  acc = make_float4(0.f, 0.f, 0.f, 0.f); l = 0.f;
  #pragma unroll
  for (int s = 0; s < NSL; ++s){
    int idx = tid + (s << 9);
    bool act = (idx < RLDS * 4);
    float uf0=0.f, uf1=0.f, uf2=0.f, uf3=0.f, d = 0.f;
    if (act){
      uint2 q2 = uj[idx];
      uf0 = blo(q2.x); uf1 = bhi(q2.x); uf2 = blo(q2.y); uf3 = bhi(q2.y);
      d = fmaf(uf0, vc0, fmaf(uf1, vc1, fmaf(uf2, vc2, uf3 * vc3)));
    }
    d = qsum4(d);
    if (act){
      float e = __expf(d - SH2);
      l += e;
      acc.x = fmaf(e, uf0, acc.x); acc.y = fmaf(e, uf1, acc.y);
      acc.z = fmaf(e, uf2, acc.z); acc.w = fmaf(e, uf3, acc.w);
    }
  }
  #pragma unroll
  for (int slot = 0; slot < NRS; ++slot){
    float d = fmaf(ur[slot][0], vc0, fmaf(ur[slot][1], vc1,
              fmaf(ur[slot][2], vc2, ur[slot][3] * vc3)));
    d = qsum4(d);
    float e = __expf(d - SH2);
    l += e;
    acc.x = fmaf(e, ur[slot][0], acc.x); acc.y = fmaf(e, ur[slot][1], acc.y);
    acc.z = fmaf(e, ur[slot][2], acc.z); acc.w = fmaf(e, ur[slot][3], acc.w);
  }
  merge_quad(acc, l, tid, red, vbuf, true, Out + ((b << 1) | k));  // logit
}

// In-place 2-way softmax over k: Out[b,0..1] fp32
__global__ void caps_softmax(float* __restrict__ Out){
  int b = blockIdx.x * blockDim.x + threadIdx.x;
  if (b < BATCH){
    float2* p = (float2*)Out;
    float2 c = p[b];
    float m  = fmaxf(c.x, c.y);
    float e0 = __expf(c.x - m), e1 = __expf(c.y - m);
    float inv = 1.f / (e0 + e1);
    p[b] = make_float2(e0 * inv, e1 * inv);
  }
}

extern "C" void kernel_launch(void* const* d_in, const int* in_sizes, int n_in,
                              void* d_out, int out_size, void* d_ws, size_t ws_size,
                              hipStream_t stream) {
  const float* U = (const float*)d_in[0];   // [1024, 2336, 4] fp32
  const float* W = (const float*)d_in[1];   // [2, 2336, 4, 16] fp32
  float* Out = (float*)d_out;               // [1024, 2] fp32
  caps_route<<<dim3(NBLK), dim3(NTH), 0, stream>>>(U, W, Out);
  caps_softmax<<<dim3(BATCH / 256), dim3(256), 0, stream>>>(Out);
}

// Round 10
// 133.210 us; speedup vs baseline: 1.8348x; 1.0579x over previous
//
#include <hip/hip_runtime.h>
#include <stdint.h>

#define RT    2336          // routes
#define RL    1184          // LDS-resident routes per batch (bf16 quads)
#define NSL2  10            // pass slices: ceil(RL*4/512); slice 9 covers 128
#define NRS2  9             // bf16 register residue slots: (RT-RL)/128 = 9
#define NTH   512
#define NBLK  1024          // one block per (b-pair, k), XCD swizzled
#define BATCH 1024
#define SH1   32.0f         // fixed softmax exponent shift, pass 2 (ratio cancels)
#define SH2   64.0f         // fixed softmax exponent shift, pass 3

__device__ __forceinline__ float blo(uint32_t v){ union {uint32_t u; float f;} x; x.u = v << 16;        return x.f; }
__device__ __forceinline__ float bhi(uint32_t v){ union {uint32_t u; float f;} x; x.u = v & 0xffff0000u; return x.f; }
__device__ __forceinline__ uint32_t f2b1(float f){          // fp32 -> bf16 (RNE)
  union {float f; uint32_t u;} x; x.f = f;
  return (x.u + 0x7fffu + ((x.u >> 16) & 1u)) >> 16;
}
__device__ __forceinline__ uint32_t f2b_pack(float a, float b){ return f2b1(a) | (f2b1(b) << 16); }
__device__ __forceinline__ uint2 pack4(float4 p){
  return make_uint2(f2b_pack(p.x, p.y), f2b_pack(p.z, p.w));
}

// Quad (4-lane) all-reduce sum via DPP quad_perm (VALU pipe, no LDS).
__device__ __forceinline__ float qsum4(float d){
  d += __int_as_float(__builtin_amdgcn_update_dpp(
         0, __float_as_int(d), 0xB1, 0xF, 0xF, true));
  d += __int_as_float(__builtin_amdgcn_update_dpp(
         0, __float_as_int(d), 0x4E, 0xF, 0xF, true));
  return d;
}

// Dual-batch block merge: batches A,B reduced in one barrier pair.
// tid<32 finishing stage: bt = tid>>4 selects batch; butterflies (masks <=8)
// stay inside each 16-lane group.
__device__ __forceinline__ void merge2(float4 aA, float lA, float4 aB, float lB,
                                       int tid, float (*red)[8][4][5],
                                       float (*vbuf)[16],
                                       bool last, float* outp){
  #pragma unroll
  for (int off = 32; off >= 4; off >>= 1){
    aA.x += __shfl_down(aA.x, off); aA.y += __shfl_down(aA.y, off);
    aA.z += __shfl_down(aA.z, off); aA.w += __shfl_down(aA.w, off);
    lA   += __shfl_down(lA,   off);
    aB.x += __shfl_down(aB.x, off); aB.y += __shfl_down(aB.y, off);
    aB.z += __shfl_down(aB.z, off); aB.w += __shfl_down(aB.w, off);
    lB   += __shfl_down(lB,   off);
  }
  const int lane = tid & 63, wid = tid >> 6;
  if (lane < 4){
    red[0][wid][lane][0] = lA;
    red[0][wid][lane][1] = aA.x; red[0][wid][lane][2] = aA.y;
    red[0][wid][lane][3] = aA.z; red[0][wid][lane][4] = aA.w;
    red[1][wid][lane][0] = lB;
    red[1][wid][lane][1] = aB.x; red[1][wid][lane][2] = aB.y;
    red[1][wid][lane][3] = aB.z; red[1][wid][lane][4] = aB.w;
  }
  __syncthreads();
  if (tid < 32){
    const int bt = tid >> 4, t = tid & 15, q = t >> 2, j = t & 3;
    float S = 0.f, partL = 0.f;
    #pragma unroll
    for (int w = 0; w < 8; ++w){
      S     += red[bt][w][q][1 + j];
      partL += red[bt][w][j][0];
    }
    partL += __shfl_xor(partL, 1);
    partL += __shfl_xor(partL, 2);
    float L   = partL * 0.25f;        // 4 qo-threads count each route once
    float inv = 1.f / L;
    float Sn  = S * inv;              // s = acc / L
    float nrm = Sn * Sn;              // squared norm over 16 outputs
    nrm += __shfl_xor(nrm, 1);
    nrm += __shfl_xor(nrm, 2);
    nrm += __shfl_xor(nrm, 4);
    nrm += __shfl_xor(nrm, 8);
    if (last){
      if (t == 0) outp[bt << 1] = nrm / (1.f + nrm);  // ||squash|| = n/(1+n)
    } else {
      float f = sqrtf(nrm) / (1.f + nrm);
      vbuf[bt][t] = Sn * f;
    }
  }
  __syncthreads();
}

// Batch-pair block: 2 batches share every W load (L2 W-traffic halves), give
// dual independent dependency chains (ILP), and halve total barriers.
// LDS 77.2 KB -> 2 blocks/CU. launch_bounds arg=2 -> VGPR cap 128 (session
// model cap=512/(2*arg)); body needs ~110 -> no spill (watch WRITE_SIZE).
__global__ void __launch_bounds__(NTH, 2)
caps_route(const float* __restrict__ U, const float* __restrict__ W,
           float* __restrict__ Out){
  __shared__ uint2 uj[2][RL * 4];     // [batch][route*4 + qo] : bf16x4
  __shared__ float red[2][8][4][5];
  __shared__ float vbuf[2][16];

  const int tid = threadIdx.x;
  const int qo  = tid & 3;            // my o-quad: o = 4*qo .. 4*qo+3

  // XCD swizzle: same XCD gets contiguous (pair,k) space; k=0/1 of one pair
  // adjacent -> u[b0],u[b1] L2 reuse; both W_k panels (1.2 MB) L2-resident.
  const int c    = blockIdx.x & 7;
  const int jj   = blockIdx.x >> 3;   // 0..127
  const int k    = jj & 1;
  const int pair = (c << 6) | (jj >> 1);   // 0..511, bijective
  const int bb   = pair << 1;         // b0 = bb, b1 = bb+1

  const float* Ub0 = U + (size_t)bb * (RT * 4);
  const float* Ub1 = Ub0 + (RT * 4);
  const float* Wk  = W + (size_t)k * ((size_t)RT * 64) + qo * 4;

  float4 accA, accB; float lA, lB;
  uint2  ura[NRS2], urb[NRS2];        // bf16-packed residue (same prec as LDS)
  float  vA0, vA1, vA2, vA3, vB0, vB1, vB2, vB3;

  // uji quads for both batches of route r; W row loaded once.
  auto build2 = [&](int route, float4& pa, float4& pb){
    float4 ua = *(const float4*)(Ub0 + (size_t)route * 4);
    float4 ub = *(const float4*)(Ub1 + (size_t)route * 4);
    const float* wr = Wk + (size_t)route * 64;
    float4 w0 = *(const float4*)(wr);
    float4 w1 = *(const float4*)(wr + 16);
    float4 w2 = *(const float4*)(wr + 32);
    float4 w3 = *(const float4*)(wr + 48);
    pa.x = ua.x * w0.x; pa.y = ua.x * w0.y; pa.z = ua.x * w0.z; pa.w = ua.x * w0.w;
    pa.x = fmaf(ua.y, w1.x, pa.x); pa.y = fmaf(ua.y, w1.y, pa.y);
    pa.z = fmaf(ua.y, w1.z, pa.z); pa.w = fmaf(ua.y, w1.w, pa.w);
    pa.x = fmaf(ua.z, w2.x, pa.x); pa.y = fmaf(ua.z, w2.y, pa.y);
    pa.z = fmaf(ua.z, w2.z, pa.z); pa.w = fmaf(ua.z, w2.w, pa.w);
    pa.x = fmaf(ua.w, w3.x, pa.x); pa.y = fmaf(ua.w, w3.y, pa.y);
    pa.z = fmaf(ua.w, w3.z, pa.z); pa.w = fmaf(ua.w, w3.w, pa.w);
    pb.x = ub.x * w0.x; pb.y = ub.x * w0.y; pb.z = ub.x * w0.z; pb.w = ub.x * w0.w;
    pb.x = fmaf(ub.y, w1.x, pb.x); pb.y = fmaf(ub.y, w1.y, pb.y);
    pb.z = fmaf(ub.y, w1.z, pb.z); pb.w = fmaf(ub.y, w1.w, pb.w);
    pb.x = fmaf(ub.z, w2.x, pb.x); pb.y = fmaf(ub.z, w2.y, pb.y);
    pb.z = fmaf(ub.z, w2.z, pb.z); pb.w = fmaf(ub.z, w2.w, pb.w);
    pb.x = fmaf(ub.w, w3.x, pb.x); pb.y = fmaf(ub.w, w3.y, pb.y);
    pb.z = fmaf(ub.w, w3.z, pb.z); pb.w = fmaf(ub.w, w3.w, pb.w);
  };

  // ---------------- Phase A: build u_ji both batches; fused pass 1 --------
  accA = make_float4(0.f,0.f,0.f,0.f); accB = make_float4(0.f,0.f,0.f,0.f);
  lA = 0.f; lB = 0.f;

  if (tid < 128){                     // pre-step: routes 0..31
    int route = tid >> 2;
    float4 pa, pb; build2(route, pa, pb);
    accA.x += pa.x; accA.y += pa.y; accA.z += pa.z; accA.w += pa.w; lA += 1.f;
    accB.x += pb.x; accB.y += pb.y; accB.z += pb.z; accB.w += pb.w; lB += 1.f;
    uj[0][route*4 + qo] = pack4(pa);
    uj[1][route*4 + qo] = pack4(pb);
  }
  #pragma unroll 3
  for (int s = 0; s < 9; ++s){        // LDS routes 32..1183
    int route = 32 + s*128 + (tid >> 2);
    float4 pa, pb; build2(route, pa, pb);
    accA.x += pa.x; accA.y += pa.y; accA.z += pa.z; accA.w += pa.w; lA += 1.f;
    accB.x += pb.x; accB.y += pb.y; accB.z += pb.z; accB.w += pb.w; lB += 1.f;
    uj[0][route*4 + qo] = pack4(pa);
    uj[1][route*4 + qo] = pack4(pb);
  }
  #pragma unroll
  for (int slot = 0; slot < NRS2; ++slot){  // reg routes 1184..2335, static
    int route = RL + slot*128 + (tid >> 2);
    float4 pa, pb; build2(route, pa, pb);
    accA.x += pa.x; accA.y += pa.y; accA.z += pa.z; accA.w += pa.w; lA += 1.f;
    accB.x += pb.x; accB.y += pb.y; accB.z += pb.z; accB.w += pb.w; lB += 1.f;
    ura[slot] = pack4(pa);
    urb[slot] = pack4(pb);
  }
  merge2(accA, lA, accB, lB, tid, red, vbuf, false, nullptr);   // v0 (A,B)
  vA0 = vbuf[0][4*qo]; vA1 = vbuf[0][4*qo+1]; vA2 = vbuf[0][4*qo+2]; vA3 = vbuf[0][4*qo+3];
  vB0 = vbuf[1][4*qo]; vB1 = vbuf[1][4*qo+1]; vB2 = vbuf[1][4*qo+2]; vB3 = vbuf[1][4*qo+3];

  // ---------------- Passes 2,3 (pass 3 uses vc = v0+v1; b starts at 0) ----
  for (int ps = 0; ps < 2; ++ps){
    const float SH = ps ? SH2 : SH1;
    accA = make_float4(0.f,0.f,0.f,0.f); accB = make_float4(0.f,0.f,0.f,0.f);
    lA = 0.f; lB = 0.f;
    #pragma unroll
    for (int s = 0; s < NSL2; ++s){   // LDS slices, idx = tid + 512*s
      int idx = tid + (s << 9);
      bool act = (idx < RL * 4);      // only s==9 partial (tid<128)
      float a0=0.f,a1=0.f,a2=0.f,a3=0.f, c0=0.f,c1=0.f,c2=0.f,c3=0.f;
      float dA = 0.f, dB = 0.f;
      if (act){
        uint2 qa = uj[0][idx], qb = uj[1][idx];
        a0 = blo(qa.x); a1 = bhi(qa.x); a2 = blo(qa.y); a3 = bhi(qa.y);
        c0 = blo(qb.x); c1 = bhi(qb.x); c2 = blo(qb.y); c3 = bhi(qb.y);
        dA = fmaf(a0, vA0, fmaf(a1, vA1, fmaf(a2, vA2, a3 * vA3)));
        dB = fmaf(c0, vB0, fmaf(c1, vB1, fmaf(c2, vB2, c3 * vB3)));
      }
      dA = qsum4(dA); dB = qsum4(dB);
      if (act){
        float eA = __expf(dA - SH), eB = __expf(dB - SH);
        lA += eA; lB += eB;
        accA.x = fmaf(eA, a0, accA.x); accA.y = fmaf(eA, a1, accA.y);
        accA.z = fmaf(eA, a2, accA.z); accA.w = fmaf(eA, a3, accA.w);
        accB.x = fmaf(eB, c0, accB.x); accB.y = fmaf(eB, c1, accB.y);
        accB.z = fmaf(eB, c2, accB.z); accB.w = fmaf(eB, c3, accB.w);
      }
    }
    #pragma unroll
    for (int slot = 0; slot < NRS2; ++slot){  // residue slices (all active)
      uint2 qa = ura[slot], qb = urb[slot];
      float a0 = blo(qa.x), a1 = bhi(qa.x), a2 = blo(qa.y), a3 = bhi(qa.y);
      float c0 = blo(qb.x), c1 = bhi(qb.x), c2 = blo(qb.y), c3 = bhi(qb.y);
      float dA = fmaf(a0, vA0, fmaf(a1, vA1, fmaf(a2, vA2, a3 * vA3)));
      float dB = fmaf(c0, vB0, fmaf(c1, vB1, fmaf(c2, vB2, c3 * vB3)));
      dA = qsum4(dA); dB = qsum4(dB);
      float eA = __expf(dA - SH), eB = __expf(dB - SH);
      lA += eA; lB += eB;
      accA.x = fmaf(eA, a0, accA.x); accA.y = fmaf(eA, a1, accA.y);
      accA.z = fmaf(eA, a2, accA.z); accA.w = fmaf(eA, a3, accA.w);
      accB.x = fmaf(eB, c0, accB.x); accB.y = fmaf(eB, c1, accB.y);
      accB.z = fmaf(eB, c2, accB.z); accB.w = fmaf(eB, c3, accB.w);
    }
    merge2(accA, lA, accB, lB, tid, red, vbuf, ps == 1,
           Out + (bb << 1) + k);      // last: Out[bb*2+k], Out[(bb+1)*2+k]
    if (ps == 0){                     // b2 = uji.(v0+v1): accumulate v
      vA0 += vbuf[0][4*qo]; vA1 += vbuf[0][4*qo+1];
      vA2 += vbuf[0][4*qo+2]; vA3 += vbuf[0][4*qo+3];
      vB0 += vbuf[1][4*qo]; vB1 += vbuf[1][4*qo+1];
      vB2 += vbuf[1][4*qo+2]; vB3 += vbuf[1][4*qo+3];
    }
  }
}

// In-place 2-way softmax over k: Out[b,0..1] fp32
__global__ void caps_softmax(float* __restrict__ Out){
  int b = blockIdx.x * blockDim.x + threadIdx.x;
  if (b < BATCH){
    float2* p = (float2*)Out;
    float2 c = p[b];
    float m  = fmaxf(c.x, c.y);
    float e0 = __expf(c.x - m), e1 = __expf(c.y - m);
    float inv = 1.f / (e0 + e1);
    p[b] = make_float2(e0 * inv, e1 * inv);
  }
}

extern "C" void kernel_launch(void* const* d_in, const int* in_sizes, int n_in,
                              void* d_out, int out_size, void* d_ws, size_t ws_size,
                              hipStream_t stream) {
  const float* U = (const float*)d_in[0];   // [1024, 2336, 4] fp32
  const float* W = (const float*)d_in[1];   // [2, 2336, 4, 16] fp32
  float* Out = (float*)d_out;               // [1024, 2] fp32
  caps_route<<<dim3(NBLK), dim3(NTH), 0, stream>>>(U, W, Out);
  caps_softmax<<<dim3(BATCH / 256), dim3(256), 0, stream>>>(Out);
}